// Round 1
// baseline (47000.656 us; speedup 1.0000x reference)
//
#include <hip/hip_runtime.h>
#include <stdint.h>
#include <limits.h>

#define BB 64
#define HH 512
#define WW 512
#define HWP (HH*WW)          // 262144
#define NPIX (BB*HWP)        // 16777216

typedef unsigned char u8;

__device__ __forceinline__ int imax(int a, int b){ return a > b ? a : b; }

// ---------------- threshold: x > -0.5 -> byte mask ----------------
__global__ void k_thresh(const float* __restrict__ x, u8* __restrict__ bin, int n4){
  int i = blockIdx.x*blockDim.x + threadIdx.x;
  if (i >= n4) return;
  float4 v = reinterpret_cast<const float4*>(x)[i];
  uchar4 o;
  o.x = (u8)(v.x > -0.5f);
  o.y = (u8)(v.y > -0.5f);
  o.z = (u8)(v.z > -0.5f);
  o.w = (u8)(v.w > -0.5f);
  reinterpret_cast<uchar4*>(bin)[i] = o;
}

// ---------------- separable morphology on byte masks ----------------
// ALL=true: erode (all R*2+1 in-bounds and set; OOB counts as 0 -> border=0)
// ALL=false: dilate (any set)
template<int R, bool ALL, bool VERT>
__global__ void k_morph(const u8* __restrict__ in, u8* __restrict__ out){
  int p = blockIdx.x*blockDim.x + threadIdx.x;
  if (p >= NPIX) return;
  int w = p % WW;
  int rest = p / WW;          // b*H + h
  int h = rest % HH;
  int bH = rest - h;          // b*H
  bool acc = ALL;
  #pragma unroll
  for (int d = -R; d <= R; ++d){
    int hh = VERT ? h + d : h;
    int ww = VERT ? w : w + d;
    bool v = false;
    if ((unsigned)hh < (unsigned)HH && (unsigned)ww < (unsigned)WW)
      v = in[(bH + hh)*WW + ww] != 0;
    acc = ALL ? (acc && v) : (acc || v);
  }
  out[p] = (u8)acc;
}

// final 5x5 erode vertical pass writing float output
__global__ void k_erode5v_f32(const u8* __restrict__ in, float* __restrict__ out){
  int p = blockIdx.x*blockDim.x + threadIdx.x;
  if (p >= NPIX) return;
  int w = p % WW;
  int rest = p / WW;
  int h = rest % HH;
  int bH = rest - h;
  bool acc = true;
  #pragma unroll
  for (int d = -2; d <= 2; ++d){
    int hh = h + d;
    bool v = false;
    if ((unsigned)hh < (unsigned)HH)
      v = in[(bH + hh)*WW + w] != 0;
    acc = acc && v;
  }
  out[p] = acc ? 1.0f : 0.0f;
}

// ---------------- seed labels ----------------
__global__ void k_seed(const u8* __restrict__ m, int* __restrict__ lab){
  int p = blockIdx.x*blockDim.x + threadIdx.x;
  if (p >= NPIX) return;
  int pw = p % HWP;                  // h*W + w
  lab[p] = m[p] ? (pw + 1) : 0;
}

// ---------------- P1: 3x3 maxpool * mask, then row run-max ----------------
// one thread per row (B*H threads). fwd scan writes forward running max,
// bwd scan (in place, on fwd result) turns it into full run-max.
__global__ void k_p1(const int* __restrict__ labIn, const u8* __restrict__ msk,
                     int* __restrict__ labOut){
  int r = blockIdx.x*blockDim.x + threadIdx.x;   // row id in [0, B*H)
  if (r >= BB*HH) return;
  int y = r % HH;
  const int* L0 = labIn + (size_t)r*WW;
  const int* Lm = (y > 0)      ? L0 - WW : nullptr;
  const int* Lp = (y < HH - 1) ? L0 + WW : nullptr;
  const u8*  M  = msk + (size_t)r*WW;
  int* O = labOut + (size_t)r*WW;

  auto colmax = [&](int x)->int {
    int v = L0[x];
    if (Lm) v = imax(v, Lm[x]);
    if (Lp) v = imax(v, Lp[x]);
    return v;
  };

  int vprev = 0;
  int vcur  = colmax(0);
  int c = 0;
  #pragma unroll 4
  for (int x = 0; x < WW; ++x){
    int vnext = (x < WW - 1) ? colmax(x + 1) : 0;
    int t = imax(vprev, imax(vcur, vnext));
    if (M[x]) { c = imax(c, t); } else { c = 0; }
    O[x] = c;
    vprev = vcur; vcur = vnext;
  }
  c = 0;
  #pragma unroll 4
  for (int x = WW - 1; x >= 0; --x){
    if (M[x]) { c = imax(c, O[x]); } else { c = 0; }
    O[x] = c;
  }
}

// ---------------- P2: column run-max ----------------
// one thread per column (B*W threads). fwd writes to labOut, bwd in place.
__global__ void k_p2(const int* __restrict__ labIn, const u8* __restrict__ msk,
                     int* __restrict__ labOut){
  int t = blockIdx.x*blockDim.x + threadIdx.x;   // column id in [0, B*W)
  if (t >= BB*WW) return;
  int b = t / WW, x = t % WW;
  const int* I = labIn + (size_t)b*HWP + x;
  const u8*  M = msk   + (size_t)b*HWP + x;
  int* O = labOut + (size_t)b*HWP + x;
  int c = 0;
  #pragma unroll 8
  for (int r = 0; r < HH; ++r){
    int v = I[(size_t)r*WW];
    u8 m = M[(size_t)r*WW];
    c = m ? imax(c, v) : 0;
    O[(size_t)r*WW] = c;
  }
  c = 0;
  #pragma unroll 8
  for (int r = HH - 1; r >= 0; --r){
    int v = O[(size_t)r*WW];
    u8 m = M[(size_t)r*WW];
    c = m ? imax(c, v) : 0;
    O[(size_t)r*WW] = c;
  }
}

// ---------------- zero areas ----------------
__global__ void k_zero(int* __restrict__ a, int n){
  int i = blockIdx.x*blockDim.x + threadIdx.x;
  int stride = gridDim.x*blockDim.x;
  for (; i < n; i += stride) a[i] = 0;
}

// ---------------- histogram (areas per label) ----------------
// 16 px per thread with run merging to reduce atomic pressure.
__global__ void k_hist(const int* __restrict__ lab, int* __restrict__ areas){
  int i = blockIdx.x*blockDim.x + threadIdx.x;
  if (i >= NPIX/16) return;
  int p = i * 16;
  int b = p / HWP;
  int* A = areas + (size_t)b*(HWP + 1);
  const int4* L = reinterpret_cast<const int4*>(lab + p);
  int cur = 0, cnt = 0;
  #pragma unroll
  for (int q = 0; q < 4; ++q){
    int4 v4 = L[q];
    int vv[4] = {v4.x, v4.y, v4.z, v4.w};
    #pragma unroll
    for (int j = 0; j < 4; ++j){
      int l = vv[j];
      if (l == cur) { cnt++; }
      else {
        if (cur > 0 && cnt) atomicAdd(&A[cur], cnt);
        cur = l; cnt = 1;
      }
    }
  }
  if (cur > 0 && cnt) atomicAdd(&A[cur], cnt);
}

// ---------------- top-2 per image ----------------
__device__ __forceinline__ void ins2(int v, int i, int& v1, int& i1, int& v2, int& i2){
  if (v > v1 || (v == v1 && i < i1)) { v2 = v1; i2 = i1; v1 = v; i1 = i; }
  else if (v > v2 || (v == v2 && i < i2)) { v2 = v; i2 = i; }
}

__global__ void k_top2(const int* __restrict__ areas, int* __restrict__ top){
  __shared__ int sv1[256], si1[256], sv2[256], si2[256];
  int b = blockIdx.x;
  const int* A = areas + (size_t)b*(HWP + 1);
  int v1 = 0, i1 = INT_MAX, v2 = 0, i2 = INT_MAX;
  for (int l = threadIdx.x; l <= HWP; l += 256){
    if (l == 0) continue;
    int v = A[l];
    if (v < 200) continue;      // MIN_AREA filter (areas < 200 -> treated as 0)
    ins2(v, l, v1, i1, v2, i2);
  }
  int t = threadIdx.x;
  sv1[t] = v1; si1[t] = i1; sv2[t] = v2; si2[t] = i2;
  __syncthreads();
  for (int s = 128; s > 0; s >>= 1){
    if (t < s){
      int a1 = sv1[t], b1 = si1[t], a2 = sv2[t], b2 = si2[t];
      ins2(sv1[t+s], si1[t+s], a1, b1, a2, b2);
      ins2(sv2[t+s], si2[t+s], a1, b1, a2, b2);
      sv1[t] = a1; si1[t] = b1; sv2[t] = a2; si2[t] = b2;
    }
    __syncthreads();
  }
  if (t == 0){
    top[b*2 + 0] = (sv1[0] >= 200) ? si1[0] : -1;
    top[b*2 + 1] = (sv2[0] >= 200) ? si2[0] : -1;
  }
}

// ---------------- keep mask ----------------
__global__ void k_keep(const int* __restrict__ lab, const int* __restrict__ top,
                       u8* __restrict__ keep){
  int i = blockIdx.x*blockDim.x + threadIdx.x;   // int4 chunks
  if (i >= NPIX/4) return;
  int b = (i * 4) / HWP;
  int t0 = top[b*2], t1 = top[b*2 + 1];
  int4 l = reinterpret_cast<const int4*>(lab)[i];
  uchar4 o;
  o.x = (u8)(l.x == t0 || l.x == t1);
  o.y = (u8)(l.y == t0 || l.y == t1);
  o.z = (u8)(l.z == t0 || l.z == t1);
  o.w = (u8)(l.w == t0 || l.w == t1);
  reinterpret_cast<uchar4*>(keep)[i] = o;
}

// ---------------- launch ----------------
extern "C" void kernel_launch(void* const* d_in, const int* in_sizes, int n_in,
                              void* d_out, int out_size, void* d_ws, size_t ws_size,
                              hipStream_t stream){
  const float* x = (const float*)d_in[0];
  float* out = (float*)d_out;
  char* ws = (char*)d_ws;

  // ws layout
  const size_t LAB0_OFF  = 0;                          // NPIX*4 = 64 MiB
  const size_t LAB1_OFF  = 67108864ull;                // NPIX*4; AREAS aliases (B*(HW+1)*4 = +256B)
  const size_t MC_OFF    = LAB1_OFF + 67109120ull;     // mask m (16 MiB)
  const size_t MA_OFF    = MC_OFF + 16777216ull;
  const size_t MB_OFF    = MA_OFF + 16777216ull;
  const size_t TOP_OFF   = MB_OFF + 16777216ull;

  int*  lab0  = (int*)(ws + LAB0_OFF);
  int*  lab1  = (int*)(ws + LAB1_OFF);
  int*  areas = (int*)(ws + LAB1_OFF);   // alias: lab1 scratch is dead after last k_p2
  u8*   mC    = (u8*)(ws + MC_OFF);      // final open mask (used by CCL)
  u8*   mA    = (u8*)(ws + MA_OFF);
  u8*   mB    = (u8*)(ws + MB_OFF);
  int*  top   = (int*)(ws + TOP_OFF);

  const int T = 256;
  dim3 blk(T);

  // 1) threshold -> mA
  k_thresh<<<dim3((NPIX/4 + T - 1)/T), blk, 0, stream>>>(x, mA, NPIX/4);
  // 2) morph open (separable): erode3 h: mA->mB ; erode3 v: mB->mC
  k_morph<1, true,  false><<<dim3((NPIX + T - 1)/T), blk, 0, stream>>>(mA, mB);
  k_morph<1, true,  true ><<<dim3((NPIX + T - 1)/T), blk, 0, stream>>>(mB, mC);
  //    dilate3 h: mC->mA ; dilate3 v: mA->mC  (mC = open mask)
  k_morph<1, false, false><<<dim3((NPIX + T - 1)/T), blk, 0, stream>>>(mC, mA);
  k_morph<1, false, true ><<<dim3((NPIX + T - 1)/T), blk, 0, stream>>>(mA, mC);
  // 3) seed labels
  k_seed<<<dim3((NPIX + T - 1)/T), blk, 0, stream>>>(mC, lab0);
  // 4) 32 CCL iterations
  for (int it = 0; it < 32; ++it){
    k_p1<<<dim3((BB*HH + T - 1)/T), blk, 0, stream>>>(lab0, mC, lab1);
    k_p2<<<dim3((BB*WW + T - 1)/T), blk, 0, stream>>>(lab1, mC, lab0);
  }
  // 5) areas histogram (areas aliases lab1 — dead now)
  k_zero<<<dim3(2048), blk, 0, stream>>>(areas, BB*(HWP + 1));
  k_hist<<<dim3((NPIX/16 + T - 1)/T), blk, 0, stream>>>(lab0, areas);
  // 6) top-2 per image
  k_top2<<<dim3(BB), blk, 0, stream>>>(areas, top);
  // 7) keep mask -> mA
  k_keep<<<dim3((NPIX/4 + T - 1)/T), blk, 0, stream>>>(lab0, top, mA);
  // 8) fill holes: dilate5 h: mA->mB ; dilate5 v: mB->mA ; erode5 h: mA->mB ; erode5 v -> out (f32)
  k_morph<2, false, false><<<dim3((NPIX + T - 1)/T), blk, 0, stream>>>(mA, mB);
  k_morph<2, false, true ><<<dim3((NPIX + T - 1)/T), blk, 0, stream>>>(mB, mA);
  k_morph<2, true,  false><<<dim3((NPIX + T - 1)/T), blk, 0, stream>>>(mA, mB);
  k_erode5v_f32<<<dim3((NPIX + T - 1)/T), blk, 0, stream>>>(mB, out);

  (void)in_sizes; (void)n_in; (void)out_size; (void)ws_size;
}

// Round 2
// 2781.952 us; speedup vs baseline: 16.8949x; 16.8949x over previous
//
#include <hip/hip_runtime.h>
#include <stdint.h>
#include <limits.h>

#define BB 64
#define HH 512
#define WW 512
#define HWP (HH*WW)          // 262144
#define NPIX (BB*HWP)        // 16777216

typedef unsigned char u8;

__device__ __forceinline__ int imax(int a, int b){ return a > b ? a : b; }

// ---------------- threshold: x > -0.5 -> byte mask ----------------
__global__ void k_thresh(const float* __restrict__ x, u8* __restrict__ bin, int n4){
  int i = blockIdx.x*blockDim.x + threadIdx.x;
  if (i >= n4) return;
  float4 v = reinterpret_cast<const float4*>(x)[i];
  uchar4 o;
  o.x = (u8)(v.x > -0.5f);
  o.y = (u8)(v.y > -0.5f);
  o.z = (u8)(v.z > -0.5f);
  o.w = (u8)(v.w > -0.5f);
  reinterpret_cast<uchar4*>(bin)[i] = o;
}

// ---------------- separable morphology on byte masks ----------------
template<int R, bool ALL, bool VERT>
__global__ void k_morph(const u8* __restrict__ in, u8* __restrict__ out){
  int p = blockIdx.x*blockDim.x + threadIdx.x;
  if (p >= NPIX) return;
  int w = p % WW;
  int rest = p / WW;          // b*H + h
  int h = rest % HH;
  int bH = rest - h;          // b*H
  bool acc = ALL;
  #pragma unroll
  for (int d = -R; d <= R; ++d){
    int hh = VERT ? h + d : h;
    int ww = VERT ? w : w + d;
    bool v = false;
    if ((unsigned)hh < (unsigned)HH && (unsigned)ww < (unsigned)WW)
      v = in[(bH + hh)*WW + ww] != 0;
    acc = ALL ? (acc && v) : (acc || v);
  }
  out[p] = (u8)acc;
}

// final 5x5 erode vertical pass writing float output
__global__ void k_erode5v_f32(const u8* __restrict__ in, float* __restrict__ out){
  int p = blockIdx.x*blockDim.x + threadIdx.x;
  if (p >= NPIX) return;
  int w = p % WW;
  int rest = p / WW;
  int h = rest % HH;
  int bH = rest - h;
  bool acc = true;
  #pragma unroll
  for (int d = -2; d <= 2; ++d){
    int hh = h + d;
    bool v = false;
    if ((unsigned)hh < (unsigned)HH)
      v = in[(bH + hh)*WW + w] != 0;
    acc = acc && v;
  }
  out[p] = acc ? 1.0f : 0.0f;
}

// ---------------- seed labels ----------------
__global__ void k_seed(const u8* __restrict__ m, int* __restrict__ lab){
  int p = blockIdx.x*blockDim.x + threadIdx.x;
  if (p >= NPIX) return;
  int pw = p % HWP;                  // h*W + w
  lab[p] = m[p] ? (pw + 1) : 0;
}

// ---------------- flags init: flags[0]=1, rest 0 ----------------
__global__ void k_initflags(int* __restrict__ flags){
  int t = threadIdx.x;
  if (t < 40) flags[t] = (t == 0) ? 1 : 0;
}

// ---------------- P1: 3x3 maxpool + per-row-run max (one wave per row) ----
// fwd-run-prop then bwd-run-prop == per-run max broadcast. One coalesced
// read of 3 rows + mask, one coalesced write. Segmented scans via shuffles.
#define P1_WAVES 4
__global__ __launch_bounds__(256)
void k_p1_seg(const int* __restrict__ labIn, const u8* __restrict__ msk,
              int* __restrict__ labOut, int* __restrict__ flags, int it){
  if (flags[it] == 0) return;
  int wid  = threadIdx.x >> 6;
  int lane = threadIdx.x & 63;
  int r = blockIdx.x * P1_WAVES + wid;        // row id in [0, B*H)
  int y = r & (HH - 1);
  const int* L0 = labIn + (size_t)r * WW;
  const u8*  M  = msk   + (size_t)r * WW;
  int xb = lane * 8;

  // center row
  int4 c0 = *reinterpret_cast<const int4*>(L0 + xb);
  int4 c1 = *reinterpret_cast<const int4*>(L0 + xb + 4);
  int v[8] = {c0.x,c0.y,c0.z,c0.w,c1.x,c1.y,c1.z,c1.w};
  // up / down rows (0 at borders, matching reduce_window zero pad)
  int uu[8] = {0,0,0,0,0,0,0,0}, dd[8] = {0,0,0,0,0,0,0,0};
  if (y > 0){
    int4 a0 = *reinterpret_cast<const int4*>(L0 - WW + xb);
    int4 a1 = *reinterpret_cast<const int4*>(L0 - WW + xb + 4);
    uu[0]=a0.x; uu[1]=a0.y; uu[2]=a0.z; uu[3]=a0.w;
    uu[4]=a1.x; uu[5]=a1.y; uu[6]=a1.z; uu[7]=a1.w;
  }
  if (y < HH - 1){
    int4 b0 = *reinterpret_cast<const int4*>(L0 + WW + xb);
    int4 b1 = *reinterpret_cast<const int4*>(L0 + WW + xb + 4);
    dd[0]=b0.x; dd[1]=b0.y; dd[2]=b0.z; dd[3]=b0.w;
    dd[4]=b1.x; dd[5]=b1.y; dd[6]=b1.z; dd[7]=b1.w;
  }
  // mask bytes
  uint2 mm = *reinterpret_cast<const uint2*>(M + xb);
  int m[8];
  #pragma unroll
  for (int j = 0; j < 4; ++j) m[j]   = (mm.x >> (8*j)) & 1;
  #pragma unroll
  for (int j = 0; j < 4; ++j) m[4+j] = (mm.y >> (8*j)) & 1;

  // vertical 3-max
  int mv[8];
  #pragma unroll
  for (int j = 0; j < 8; ++j) mv[j] = imax(v[j], imax(uu[j], dd[j]));
  // horizontal 3-max (neighbors across lanes)
  int left  = __shfl_up(mv[7], 1);  if (lane == 0)  left  = 0;
  int right = __shfl_down(mv[0], 1); if (lane == 63) right = 0;
  int t[8];
  #pragma unroll
  for (int j = 0; j < 8; ++j){
    int a = (j == 0) ? left  : mv[j-1];
    int b = (j == 7) ? right : mv[j+1];
    t[j] = imax(mv[j], imax(a, b));
  }

  int allm = m[0]&m[1]&m[2]&m[3]&m[4]&m[5]&m[6]&m[7];

  // ---- forward segmented scan ----
  int F[8]; int c = 0;
  #pragma unroll
  for (int j = 0; j < 8; ++j){ c = m[j] ? imax(c, t[j]) : 0; F[j] = c; }
  int sv = F[7], sb = !allm;
  #pragma unroll
  for (int d = 1; d < 64; d <<= 1){
    int ov = __shfl_up(sv, d);
    int ob = __shfl_up(sb, d);
    if (lane >= d){ if (!sb) sv = imax(sv, ov); sb |= ob; }
  }
  int pF = __shfl_up(sv, 1); if (lane == 0) pF = 0;
  {
    bool pass = true;
    #pragma unroll
    for (int j = 0; j < 8; ++j){
      if (!m[j]) pass = false;
      else if (pass) F[j] = imax(F[j], pF);
    }
  }

  // ---- backward segmented scan ----
  int G[8]; c = 0;
  #pragma unroll
  for (int j = 7; j >= 0; --j){ c = m[j] ? imax(c, t[j]) : 0; G[j] = c; }
  sv = G[0]; sb = !allm;
  #pragma unroll
  for (int d = 1; d < 64; d <<= 1){
    int ov = __shfl_down(sv, d);
    int ob = __shfl_down(sb, d);
    if (lane < 64 - d){ if (!sb) sv = imax(sv, ov); sb |= ob; }
  }
  int pG = __shfl_down(sv, 1); if (lane == 63) pG = 0;
  {
    bool pass = true;
    #pragma unroll
    for (int j = 7; j >= 0; --j){
      if (!m[j]) pass = false;
      else if (pass) G[j] = imax(G[j], pG);
    }
  }

  // output = per-run max; detect change vs input
  bool changed = false;
  int4 o0, o1;
  int o[8];
  #pragma unroll
  for (int j = 0; j < 8; ++j){
    o[j] = imax(F[j], G[j]);
    changed |= (o[j] != v[j]);
  }
  o0.x=o[0]; o0.y=o[1]; o0.z=o[2]; o0.w=o[3];
  o1.x=o[4]; o1.y=o[5]; o1.z=o[6]; o1.w=o[7];
  int* O = labOut + (size_t)r * WW + xb;
  *reinterpret_cast<int4*>(O)     = o0;
  *reinterpret_cast<int4*>(O + 4) = o1;

  unsigned long long bl = __ballot(changed);
  if (lane == 0 && bl) atomicOr(&flags[it + 1], 1);
}

// ---------------- P2: column run-max (thread per column, coalesced) -------
__global__ __launch_bounds__(256)
void k_p2(const int* __restrict__ labIn, const u8* __restrict__ msk,
          int* __restrict__ labOut, int* __restrict__ flags, int it){
  if (flags[it] == 0) return;
  int tid = blockIdx.x*blockDim.x + threadIdx.x;   // column id in [0, B*W)
  int b = tid >> 9, x = tid & (WW - 1);
  const int* I = labIn + (size_t)b*HWP + x;
  const u8*  M = msk   + (size_t)b*HWP + x;
  int* O = labOut + (size_t)b*HWP + x;
  bool changed = false;
  int c = 0;
  #pragma unroll 8
  for (int r = 0; r < HH; ++r){
    int v = I[(size_t)r*WW];
    u8 mk = M[(size_t)r*WW];
    c = mk ? imax(c, v) : 0;
    changed |= (c != v);
    O[(size_t)r*WW] = c;
  }
  c = 0;
  #pragma unroll 8
  for (int r = HH - 1; r >= 0; --r){
    int v = O[(size_t)r*WW];
    u8 mk = M[(size_t)r*WW];
    c = mk ? imax(c, v) : 0;
    changed |= (c != v);
    O[(size_t)r*WW] = c;
  }
  unsigned long long bl = __ballot(changed);
  if ((threadIdx.x & 63) == 0 && bl) atomicOr(&flags[it + 1], 1);
}

// ---------------- zero areas ----------------
__global__ void k_zero(int* __restrict__ a, int n){
  int i = blockIdx.x*blockDim.x + threadIdx.x;
  int stride = gridDim.x*blockDim.x;
  for (; i < n; i += stride) a[i] = 0;
}

// ---------------- histogram (areas per label) ----------------
__global__ void k_hist(const int* __restrict__ lab, int* __restrict__ areas){
  int i = blockIdx.x*blockDim.x + threadIdx.x;
  if (i >= NPIX/16) return;
  int p = i * 16;
  int b = p / HWP;
  int* A = areas + (size_t)b*(HWP + 1);
  const int4* L = reinterpret_cast<const int4*>(lab + p);
  int cur = 0, cnt = 0;
  #pragma unroll
  for (int q = 0; q < 4; ++q){
    int4 v4 = L[q];
    int vv[4] = {v4.x, v4.y, v4.z, v4.w};
    #pragma unroll
    for (int j = 0; j < 4; ++j){
      int l = vv[j];
      if (l == cur) { cnt++; }
      else {
        if (cur > 0 && cnt) atomicAdd(&A[cur], cnt);
        cur = l; cnt = 1;
      }
    }
  }
  if (cur > 0 && cnt) atomicAdd(&A[cur], cnt);
}

// ---------------- top-2 per image ----------------
__device__ __forceinline__ void ins2(int v, int i, int& v1, int& i1, int& v2, int& i2){
  if (v > v1 || (v == v1 && i < i1)) { v2 = v1; i2 = i1; v1 = v; i1 = i; }
  else if (v > v2 || (v == v2 && i < i2)) { v2 = v; i2 = i; }
}

__global__ void k_top2(const int* __restrict__ areas, int* __restrict__ top){
  __shared__ int sv1[256], si1[256], sv2[256], si2[256];
  int b = blockIdx.x;
  const int* A = areas + (size_t)b*(HWP + 1);
  int v1 = 0, i1 = INT_MAX, v2 = 0, i2 = INT_MAX;
  for (int l = threadIdx.x; l <= HWP; l += 256){
    if (l == 0) continue;
    int v = A[l];
    if (v < 200) continue;
    ins2(v, l, v1, i1, v2, i2);
  }
  int t = threadIdx.x;
  sv1[t] = v1; si1[t] = i1; sv2[t] = v2; si2[t] = i2;
  __syncthreads();
  for (int s = 128; s > 0; s >>= 1){
    if (t < s){
      int a1 = sv1[t], b1 = si1[t], a2 = sv2[t], b2 = si2[t];
      ins2(sv1[t+s], si1[t+s], a1, b1, a2, b2);
      ins2(sv2[t+s], si2[t+s], a1, b1, a2, b2);
      sv1[t] = a1; si1[t] = b1; sv2[t] = a2; si2[t] = b2;
    }
    __syncthreads();
  }
  if (t == 0){
    top[b*2 + 0] = (sv1[0] >= 200) ? si1[0] : -1;
    top[b*2 + 1] = (sv2[0] >= 200) ? si2[0] : -1;
  }
}

// ---------------- keep mask ----------------
__global__ void k_keep(const int* __restrict__ lab, const int* __restrict__ top,
                       u8* __restrict__ keep){
  int i = blockIdx.x*blockDim.x + threadIdx.x;   // int4 chunks
  if (i >= NPIX/4) return;
  int b = (i * 4) / HWP;
  int t0 = top[b*2], t1 = top[b*2 + 1];
  int4 l = reinterpret_cast<const int4*>(lab)[i];
  uchar4 o;
  o.x = (u8)(l.x == t0 || l.x == t1);
  o.y = (u8)(l.y == t0 || l.y == t1);
  o.z = (u8)(l.z == t0 || l.z == t1);
  o.w = (u8)(l.w == t0 || l.w == t1);
  reinterpret_cast<uchar4*>(keep)[i] = o;
}

// ---------------- launch ----------------
extern "C" void kernel_launch(void* const* d_in, const int* in_sizes, int n_in,
                              void* d_out, int out_size, void* d_ws, size_t ws_size,
                              hipStream_t stream){
  const float* x = (const float*)d_in[0];
  float* out = (float*)d_out;
  char* ws = (char*)d_ws;

  // ws layout
  const size_t LAB0_OFF  = 0;                          // NPIX*4 = 64 MiB
  const size_t LAB1_OFF  = 67108864ull;                // NPIX*4; AREAS aliases
  const size_t MC_OFF    = LAB1_OFF + 67109120ull;
  const size_t MA_OFF    = MC_OFF + 16777216ull;
  const size_t MB_OFF    = MA_OFF + 16777216ull;
  const size_t TOP_OFF   = MB_OFF + 16777216ull;
  const size_t FLAGS_OFF = TOP_OFF + 1024ull;

  int*  lab0  = (int*)(ws + LAB0_OFF);
  int*  lab1  = (int*)(ws + LAB1_OFF);
  int*  areas = (int*)(ws + LAB1_OFF);   // alias: lab1 dead after last k_p2
  u8*   mC    = (u8*)(ws + MC_OFF);      // open mask (used by CCL)
  u8*   mA    = (u8*)(ws + MA_OFF);
  u8*   mB    = (u8*)(ws + MB_OFF);
  int*  top   = (int*)(ws + TOP_OFF);
  int*  flags = (int*)(ws + FLAGS_OFF);

  const int T = 256;
  dim3 blk(T);

  // 1) threshold -> mA
  k_thresh<<<dim3((NPIX/4 + T - 1)/T), blk, 0, stream>>>(x, mA, NPIX/4);
  // 2) morph open: erode3 h mA->mB ; erode3 v mB->mC ; dilate3 h mC->mA ; dilate3 v mA->mC
  k_morph<1, true,  false><<<dim3((NPIX + T - 1)/T), blk, 0, stream>>>(mA, mB);
  k_morph<1, true,  true ><<<dim3((NPIX + T - 1)/T), blk, 0, stream>>>(mB, mC);
  k_morph<1, false, false><<<dim3((NPIX + T - 1)/T), blk, 0, stream>>>(mC, mA);
  k_morph<1, false, true ><<<dim3((NPIX + T - 1)/T), blk, 0, stream>>>(mA, mC);
  // 3) seed labels + flags
  k_seed<<<dim3((NPIX + T - 1)/T), blk, 0, stream>>>(mC, lab0);
  k_initflags<<<dim3(1), dim3(64), 0, stream>>>(flags);
  // 4) 32 CCL iterations (skip once converged; provably identity afterwards)
  for (int it = 0; it < 32; ++it){
    k_p1_seg<<<dim3(BB*HH/P1_WAVES), blk, 0, stream>>>(lab0, mC, lab1, flags, it);
    k_p2<<<dim3((BB*WW)/T), blk, 0, stream>>>(lab1, mC, lab0, flags, it);
  }
  // 5) areas histogram (areas aliases lab1 — dead now)
  k_zero<<<dim3(2048), blk, 0, stream>>>(areas, BB*(HWP + 1));
  k_hist<<<dim3((NPIX/16 + T - 1)/T), blk, 0, stream>>>(lab0, areas);
  // 6) top-2 per image
  k_top2<<<dim3(BB), blk, 0, stream>>>(areas, top);
  // 7) keep mask -> mA
  k_keep<<<dim3((NPIX/4 + T - 1)/T), blk, 0, stream>>>(lab0, top, mA);
  // 8) fill holes: dilate5 h/v, erode5 h, erode5 v -> f32 out
  k_morph<2, false, false><<<dim3((NPIX + T - 1)/T), blk, 0, stream>>>(mA, mB);
  k_morph<2, false, true ><<<dim3((NPIX + T - 1)/T), blk, 0, stream>>>(mB, mA);
  k_morph<2, true,  false><<<dim3((NPIX + T - 1)/T), blk, 0, stream>>>(mA, mB);
  k_erode5v_f32<<<dim3((NPIX + T - 1)/T), blk, 0, stream>>>(mB, out);

  (void)in_sizes; (void)n_in; (void)out_size; (void)ws_size;
}

// Round 3
// 738.367 us; speedup vs baseline: 63.6549x; 3.7677x over previous
//
#include <hip/hip_runtime.h>
#include <stdint.h>
#include <limits.h>

#define BB 64
#define HH 512
#define WW 512
#define HWP (HH*WW)          // 262144
#define NPIX (BB*HWP)        // 16777216
#define NROWS (BB*HH)        // 32768
#define RUNSTRIDE 136        // max runs/row = 128 (opened mask: run len >= 3), padded
#define MAXRUNS (NROWS*RUNSTRIDE)

typedef unsigned char u8;
typedef unsigned long long u64;

__device__ __forceinline__ int imax(int a, int b){ return a > b ? a : b; }

// ---------------- threshold: x > -0.5 -> byte mask ----------------
__global__ void k_thresh(const float* __restrict__ x, u8* __restrict__ bin, int n4){
  int i = blockIdx.x*blockDim.x + threadIdx.x;
  if (i >= n4) return;
  float4 v = reinterpret_cast<const float4*>(x)[i];
  uchar4 o;
  o.x = (u8)(v.x > -0.5f);
  o.y = (u8)(v.y > -0.5f);
  o.z = (u8)(v.z > -0.5f);
  o.w = (u8)(v.w > -0.5f);
  reinterpret_cast<uchar4*>(bin)[i] = o;
}

// ---------------- separable morphology on byte masks ----------------
template<int R, bool ALL, bool VERT>
__global__ void k_morph(const u8* __restrict__ in, u8* __restrict__ out){
  int p = blockIdx.x*blockDim.x + threadIdx.x;
  if (p >= NPIX) return;
  int w = p % WW;
  int rest = p / WW;          // b*H + h
  int h = rest % HH;
  int bH = rest - h;          // b*H
  bool acc = ALL;
  #pragma unroll
  for (int d = -R; d <= R; ++d){
    int hh = VERT ? h + d : h;
    int ww = VERT ? w : w + d;
    bool v = false;
    if ((unsigned)hh < (unsigned)HH && (unsigned)ww < (unsigned)WW)
      v = in[(bH + hh)*WW + ww] != 0;
    acc = ALL ? (acc && v) : (acc || v);
  }
  out[p] = (u8)acc;
}

// final 5x5 erode vertical pass writing float output
__global__ void k_erode5v_f32(const u8* __restrict__ in, float* __restrict__ out){
  int p = blockIdx.x*blockDim.x + threadIdx.x;
  if (p >= NPIX) return;
  int w = p % WW;
  int rest = p / WW;
  int h = rest % HH;
  int bH = rest - h;
  bool acc = true;
  #pragma unroll
  for (int d = -2; d <= 2; ++d){
    int hh = h + d;
    bool v = false;
    if ((unsigned)hh < (unsigned)HH)
      v = in[(bH + hh)*WW + w] != 0;
    acc = acc && v;
  }
  out[p] = acc ? 1.0f : 0.0f;
}

// ---------------- bit-pack mask: 8 bytes -> 1 byte of bits ----------------
__global__ void k_bitify(const u8* __restrict__ m, u8* __restrict__ bits, int n8){
  int i = blockIdx.x*blockDim.x + threadIdx.x;
  if (i >= n8) return;
  uint2 w2 = reinterpret_cast<const uint2*>(m)[i];
  u64 w = ((u64)w2.y << 32) | w2.x;
  bits[i] = (u8)((w * 0x0102040810204080ULL) >> 56);   // LSB of byte j -> bit j
}

// ---------------- run extraction (thread per row) ----------------
// emits [start,end] per maximal run; inits parent/area/clabel for emitted ids
__global__ void k_runs(const u64* __restrict__ bitrow, uint32_t* __restrict__ runs,
                       int* __restrict__ parent, int* __restrict__ area,
                       int* __restrict__ clabel, int* __restrict__ cnt){
  int r = blockIdx.x*blockDim.x + threadIdx.x;
  if (r >= NROWS) return;
  const u64* W = bitrow + (size_t)r*8;
  u64 w[8];
  #pragma unroll
  for (int i = 0; i < 8; ++i) w[i] = W[i];
  int base = r*RUNSTRIDE;
  int k = 0;
  int pending = -1;
  u64 carry = 0;
  #pragma unroll
  for (int wi = 0; wi < 8; ++wi){
    u64 b = w[wi];
    u64 nb0 = (wi < 7) ? (w[wi+1] & 1ULL) : 0ULL;
    u64 starts = b & ~((b << 1) | carry);
    u64 ends   = b & ~(b >> 1);
    if (nb0) ends &= ~(1ULL << 63);
    carry = b >> 63;
    while (ends){
      int e = __ffsll(ends) - 1; ends &= ends - 1;
      int s;
      if (pending >= 0){ s = pending; pending = -1; }
      else { s = wi*64 + (__ffsll(starts) - 1); starts &= starts - 1; }
      int id = base + k;
      runs[id] = (uint32_t)s | ((uint32_t)(wi*64 + e) << 16);
      parent[id] = id; area[id] = 0; clabel[id] = 0;
      k++;
    }
    if (starts) pending = wi*64 + (__ffsll(starts) - 1);
  }
  cnt[r] = k;
}

// ---------------- union-find helpers ----------------
__device__ __forceinline__ int uf_find(const int* parent, int p){
  while (true){ int q = parent[p]; if (q == p) return p; p = q; }
}
__device__ __forceinline__ void uf_union(int* parent, int a, int b){
  while (true){
    a = uf_find(parent, a);
    b = uf_find(parent, b);
    if (a == b) return;
    if (a < b){ int t = a; a = b; b = t; }     // a = hi, b = lo
    int old = atomicMin(&parent[a], b);
    if (old == a) return;
    a = old;                                    // continue union(old, b)
  }
}

// ---------------- link runs between adjacent rows (8-conn) ----------------
__global__ void k_link(const uint32_t* __restrict__ runs, const int* __restrict__ cnt,
                       int* __restrict__ parent){
  int t = blockIdx.x*blockDim.x + threadIdx.x;
  if (t >= NROWS) return;
  int y = t & (HH - 1);
  if (y == 0) return;
  int ca = cnt[t], cb = cnt[t-1];
  int baseA = t*RUNSTRIDE, baseB = (t-1)*RUNSTRIDE;
  int i = 0, j = 0;
  while (i < ca && j < cb){
    uint32_t ra = runs[baseA+i]; int sA = ra & 0xffff, eA = ra >> 16;
    uint32_t rb = runs[baseB+j]; int sB = rb & 0xffff, eB = rb >> 16;
    if (sB <= eA + 1 && sA <= eB + 1) uf_union(parent, baseA+i, baseB+j);
    if (eA <= eB) i++; else j++;
  }
}

// ---------------- flatten + accumulate area / component label -------------
__global__ void k_flatten(const uint32_t* __restrict__ runs, const int* __restrict__ cnt,
                          int* __restrict__ parent, int* __restrict__ area,
                          int* __restrict__ clabel){
  int r = blockIdx.x*blockDim.x + threadIdx.x;
  if (r >= NROWS) return;
  int y = r & (HH - 1);
  int base = r*RUNSTRIDE;
  int n = cnt[r];
  for (int k = 0; k < n; ++k){
    int id = base + k;
    int root = uf_find(parent, id);
    parent[id] = root;
    uint32_t run = runs[id]; int s = run & 0xffff, e = run >> 16;
    atomicAdd(&area[root], e - s + 1);
    atomicMax(&clabel[root], y*WW + e + 1);
  }
}

// ---------------- top-2 components per image ----------------
__device__ __forceinline__ void ins2(int v, int i, int& v1, int& i1, int& v2, int& i2){
  if (v > v1 || (v == v1 && i < i1)) { v2 = v1; i2 = i1; v1 = v; i1 = i; }
  else if (v > v2 || (v == v2 && i < i2)) { v2 = v; i2 = i; }
}

__global__ void k_top2c(const int* __restrict__ cnt, const int* __restrict__ parent,
                        const int* __restrict__ area, const int* __restrict__ clabel,
                        int* __restrict__ keepL){
  __shared__ int sv1[256], si1[256], sv2[256], si2[256];
  int b = blockIdx.x;
  int v1 = 0, i1 = INT_MAX, v2 = 0, i2 = INT_MAX;
  for (int y = threadIdx.x; y < HH; y += 256){
    int row = b*HH + y;
    int base = row*RUNSTRIDE;
    int n = cnt[row];
    for (int k = 0; k < n; ++k){
      int id = base + k;
      if (parent[id] != id) continue;        // roots only
      int a = area[id];
      if (a < 200) continue;                 // MIN_AREA
      ins2(a, clabel[id], v1, i1, v2, i2);
    }
  }
  int t = threadIdx.x;
  sv1[t] = v1; si1[t] = i1; sv2[t] = v2; si2[t] = i2;
  __syncthreads();
  for (int s = 128; s > 0; s >>= 1){
    if (t < s){
      int a1 = sv1[t], b1 = si1[t], a2 = sv2[t], b2 = si2[t];
      ins2(sv1[t+s], si1[t+s], a1, b1, a2, b2);
      ins2(sv2[t+s], si2[t+s], a1, b1, a2, b2);
      sv1[t] = a1; si1[t] = b1; sv2[t] = a2; si2[t] = b2;
    }
    __syncthreads();
  }
  if (t == 0){
    keepL[b*2 + 0] = (sv1[0] >= 200) ? si1[0] : 0;   // 0 = invalid (labels >= 1)
    keepL[b*2 + 1] = (sv2[0] >= 200) ? si2[0] : 0;
  }
}

// ---------------- paint keep mask rows from kept runs ----------------
__device__ __forceinline__ u64 rmask(int s, int e){  // bits s..e inclusive
  u64 hi = (e >= 63) ? ~0ULL : ((1ULL << (e + 1)) - 1);
  u64 lo = (1ULL << s) - 1;
  return hi & ~lo;
}

__global__ void k_keep_rows(const uint32_t* __restrict__ runs, const int* __restrict__ cnt,
                            const int* __restrict__ parent, const int* __restrict__ clabel,
                            const int* __restrict__ keepL, u8* __restrict__ keep){
  int r = blockIdx.x*blockDim.x + threadIdx.x;
  if (r >= NROWS) return;
  int b = r >> 9;
  int L1 = keepL[b*2], L2 = keepL[b*2 + 1];
  u64 bits[8] = {0,0,0,0,0,0,0,0};
  int base = r*RUNSTRIDE;
  int n = cnt[r];
  for (int k = 0; k < n; ++k){
    int id = base + k;
    int L = clabel[parent[id]];
    if (L != L1 && L != L2) continue;
    uint32_t run = runs[id]; int s = run & 0xffff, e = run >> 16;
    int w0 = s >> 6, w1 = e >> 6;
    if (w0 == w1) bits[w0] |= rmask(s & 63, e & 63);
    else {
      bits[w0] |= rmask(s & 63, 63);
      for (int wi = w0 + 1; wi < w1; ++wi) bits[wi] = ~0ULL;
      bits[w1] |= rmask(0, e & 63);
    }
  }
  u64* O = reinterpret_cast<u64*>(keep + (size_t)r*WW);
  #pragma unroll
  for (int wi = 0; wi < 8; ++wi){
    u64 bb = bits[wi];
    #pragma unroll
    for (int q = 0; q < 8; ++q){
      u64 ow = 0;
      #pragma unroll
      for (int j = 0; j < 8; ++j)
        ow |= ((bb >> (q*8 + j)) & 1ULL) << (8*j);
      O[wi*8 + q] = ow;
    }
  }
}

// ---------------- launch ----------------
extern "C" void kernel_launch(void* const* d_in, const int* in_sizes, int n_in,
                              void* d_out, int out_size, void* d_ws, size_t ws_size,
                              hipStream_t stream){
  const float* x = (const float*)d_in[0];
  float* out = (float*)d_out;
  char* ws = (char*)d_ws;

  // ws layout
  const size_t MA_OFF     = 0;                         // 16 MiB
  const size_t MB_OFF     = MA_OFF + 16777216ull;      // 16 MiB
  const size_t MC_OFF     = MB_OFF + 16777216ull;      // 16 MiB
  const size_t BIT_OFF    = MC_OFF + 16777216ull;      // 2 MiB
  const size_t RUNS_OFF   = BIT_OFF + 2097152ull;      // MAXRUNS*4 ~ 17.8 MB
  const size_t PAR_OFF    = RUNS_OFF + (size_t)MAXRUNS*4;
  const size_t AREA_OFF   = PAR_OFF  + (size_t)MAXRUNS*4;
  const size_t CLAB_OFF   = AREA_OFF + (size_t)MAXRUNS*4;
  const size_t CNT_OFF    = CLAB_OFF + (size_t)MAXRUNS*4;
  const size_t KEEPL_OFF  = CNT_OFF  + (size_t)NROWS*4;

  u8*       mA     = (u8*)(ws + MA_OFF);
  u8*       mB     = (u8*)(ws + MB_OFF);
  u8*       mC     = (u8*)(ws + MC_OFF);     // opened mask
  u64*      bitrow = (u64*)(ws + BIT_OFF);
  uint32_t* runs   = (uint32_t*)(ws + RUNS_OFF);
  int*      parent = (int*)(ws + PAR_OFF);
  int*      area   = (int*)(ws + AREA_OFF);
  int*      clabel = (int*)(ws + CLAB_OFF);
  int*      cnt    = (int*)(ws + CNT_OFF);
  int*      keepL  = (int*)(ws + KEEPL_OFF);

  const int T = 256;
  dim3 blk(T);

  // 1) threshold -> mA
  k_thresh<<<dim3(NPIX/4/T), blk, 0, stream>>>(x, mA, NPIX/4);
  // 2) morph open: erode3 h mA->mB ; erode3 v mB->mC ; dilate3 h mC->mA ; dilate3 v mA->mC
  k_morph<1, true,  false><<<dim3(NPIX/T), blk, 0, stream>>>(mA, mB);
  k_morph<1, true,  true ><<<dim3(NPIX/T), blk, 0, stream>>>(mB, mC);
  k_morph<1, false, false><<<dim3(NPIX/T), blk, 0, stream>>>(mC, mA);
  k_morph<1, false, true ><<<dim3(NPIX/T), blk, 0, stream>>>(mA, mC);
  // 3) CCL via runs + union-find (fixpoint of reference's converged iteration)
  k_bitify<<<dim3(NPIX/8/T), blk, 0, stream>>>(mC, (u8*)bitrow, NPIX/8);
  k_runs<<<dim3(NROWS/T), blk, 0, stream>>>(bitrow, runs, parent, area, clabel, cnt);
  k_link<<<dim3(NROWS/T), blk, 0, stream>>>(runs, cnt, parent);
  k_flatten<<<dim3(NROWS/T), blk, 0, stream>>>(runs, cnt, parent, area, clabel);
  k_top2c<<<dim3(BB), blk, 0, stream>>>(cnt, parent, area, clabel, keepL);
  k_keep_rows<<<dim3(NROWS/T), blk, 0, stream>>>(runs, cnt, parent, clabel, keepL, mA);
  // 4) fill holes: dilate5 h mA->mB ; dilate5 v mB->mA ; erode5 h mA->mB ; erode5 v -> f32 out
  k_morph<2, false, false><<<dim3(NPIX/T), blk, 0, stream>>>(mA, mB);
  k_morph<2, false, true ><<<dim3(NPIX/T), blk, 0, stream>>>(mB, mA);
  k_morph<2, true,  false><<<dim3(NPIX/T), blk, 0, stream>>>(mA, mB);
  k_erode5v_f32<<<dim3(NPIX/T), blk, 0, stream>>>(mB, out);

  (void)in_sizes; (void)n_in; (void)out_size; (void)ws_size;
}

// Round 4
// 168.122 us; speedup vs baseline: 279.5630x; 4.3919x over previous
//
#include <hip/hip_runtime.h>
#include <stdint.h>
#include <limits.h>

#define BB 64
#define HH 512
#define WW 512
#define WPR 8                  // 64-bit words per row
#define HWP (HH*WW)            // 262144
#define NPIX (BB*HWP)          // 16777216
#define NROWS (BB*HH)          // 32768
#define NWORDS (NROWS*WPR)     // 262144
#define RS 128                 // exact max runs/row in opened mask (len>=3, gap>=1)
#define MAXRUNS (NROWS*RS)     // 4194304
#define MAXROOTS 2048          // >= 262144/200 + slack

typedef unsigned char u8;
typedef unsigned long long u64;

__device__ __forceinline__ int imax(int a, int b){ return a > b ? a : b; }

// ---------------- init: parent identity, area/clabel 0, keepbits 0 --------
__global__ void k_init(int* __restrict__ parent, int* __restrict__ area,
                       int* __restrict__ clabel, u64* __restrict__ keepbits,
                       int* __restrict__ rootcnt){
  int t = blockIdx.x*blockDim.x + threadIdx.x;
  if (t < MAXRUNS){ parent[t] = t; area[t] = 0; clabel[t] = 0; }
  if (t < NWORDS) keepbits[t] = 0;
  if (t < BB) rootcnt[t] = 0;
}

// ---------------- threshold + bit-pack via ballot ----------------
__global__ void k_threshpack(const float* __restrict__ x, u64* __restrict__ bits){
  int g = blockIdx.x*blockDim.x + threadIdx.x;    // one thread per pixel
  float v = x[g];
  u64 b = __ballot(v > -0.5f);
  if ((threadIdx.x & 63) == 0) bits[g >> 6] = b;
}

// ---------------- bit-domain fused 2D morphology ----------------
// R: radius (1 or 2). ERODE: AND over (2R+1)^2 window, zero pad. else OR.
template<int R, bool ERODE>
__global__ void k_bmorph(const u64* __restrict__ in, u64* __restrict__ out){
  int t = blockIdx.x*blockDim.x + threadIdx.x;
  if (t >= NWORDS) return;
  int wi = t & 7;
  int row = t >> 3;
  int y = row & (HH - 1);
  u64 acc = ERODE ? ~0ULL : 0ULL;
  #pragma unroll
  for (int dy = -R; dy <= R; ++dy){
    int yy = y + dy;
    u64 h;
    if ((unsigned)yy >= (unsigned)HH){
      h = 0ULL;                                   // zero pad row
    } else {
      const u64* Rw = in + (size_t)(row + dy)*WPR;
      u64 c = Rw[wi];
      u64 l = (wi > 0) ? Rw[wi-1] : 0ULL;
      u64 r = (wi < 7) ? Rw[wi+1] : 0ULL;
      u64 s1l = (c << 1) | (l >> 63);
      u64 s1r = (c >> 1) | (r << 63);
      if (ERODE) h = c & s1l & s1r; else h = c | s1l | s1r;
      if (R == 2){
        u64 s2l = (c << 2) | (l >> 62);
        u64 s2r = (c >> 2) | (r << 62);
        if (ERODE) h = h & s2l & s2r; else h = h | s2l | s2r;
      }
    }
    if (ERODE) acc &= h; else acc |= h;
  }
  out[t] = acc;
}

// ---------------- run extraction (thread per row, bit input) --------------
__global__ void k_runs(const u64* __restrict__ bitrow, uint32_t* __restrict__ runs,
                       int* __restrict__ cnt){
  int r = blockIdx.x*blockDim.x + threadIdx.x;
  if (r >= NROWS) return;
  const u64* W = bitrow + (size_t)r*WPR;
  u64 w[8];
  #pragma unroll
  for (int i = 0; i < 8; ++i) w[i] = W[i];
  int base = r*RS;
  int k = 0;
  int pending = -1;
  u64 carry = 0;
  #pragma unroll
  for (int wi = 0; wi < 8; ++wi){
    u64 b = w[wi];
    u64 nb0 = (wi < 7) ? (w[wi+1] & 1ULL) : 0ULL;
    u64 starts = b & ~((b << 1) | carry);
    u64 ends   = b & ~(b >> 1);
    if (nb0) ends &= ~(1ULL << 63);
    carry = b >> 63;
    while (ends){
      int e = __ffsll((long long)ends) - 1; ends &= ends - 1;
      int s;
      if (pending >= 0){ s = pending; pending = -1; }
      else { s = wi*64 + (__ffsll((long long)starts) - 1); starts &= starts - 1; }
      runs[base + k] = (uint32_t)s | ((uint32_t)(wi*64 + e) << 16);
      k++;
    }
    if (starts) pending = wi*64 + (__ffsll((long long)starts) - 1);
  }
  cnt[r] = k;
}

// ---------------- union-find ----------------
__device__ __forceinline__ int uf_find(const int* parent, int p){
  while (true){ int q = parent[p]; if (q == p) return p; p = q; }
}
__device__ __forceinline__ void uf_union(int* parent, int a, int b){
  while (true){
    a = uf_find(parent, a);
    b = uf_find(parent, b);
    if (a == b) return;
    if (a < b){ int t = a; a = b; b = t; }     // a = hi, b = lo
    int old = atomicMin(&parent[a], b);
    if (old == a) return;
    a = old;
  }
}

// ---------------- link runs to previous row (thread per run slot) ---------
__global__ void k_link(const uint32_t* __restrict__ runs, const int* __restrict__ cnt,
                       int* __restrict__ parent){
  int t = blockIdx.x*blockDim.x + threadIdx.x;
  if (t >= MAXRUNS) return;
  int r = t >> 7, k = t & (RS - 1);
  int y = r & (HH - 1);
  if (y == 0) return;
  if (k >= cnt[r]) return;
  int cb = cnt[r-1];
  if (cb == 0) return;
  uint32_t ra = runs[t]; int sA = (int)(ra & 0xffff), eA = (int)(ra >> 16);
  const uint32_t* RB = runs + (size_t)(r-1)*RS;
  // first j with eB_j >= sA-1 (ends strictly increasing)
  int lo = 0, hi = cb, target = sA - 1;
  while (lo < hi){
    int mid = (lo + hi) >> 1;
    if ((int)(RB[mid] >> 16) < target) lo = mid + 1; else hi = mid;
  }
  for (int j = lo; j < cb; ++j){
    uint32_t rb = RB[j];
    if ((int)(rb & 0xffff) > eA + 1) break;
    uf_union(parent, t, (r-1)*RS + j);
  }
}

// ---------------- flatten + accumulate (thread per run slot) --------------
__global__ void k_flatten(const uint32_t* __restrict__ runs, const int* __restrict__ cnt,
                          int* __restrict__ parent, int* __restrict__ area,
                          int* __restrict__ clabel){
  int t = blockIdx.x*blockDim.x + threadIdx.x;
  if (t >= MAXRUNS) return;
  int r = t >> 7, k = t & (RS - 1);
  if (k >= cnt[r]) return;
  int root = uf_find(parent, t);
  parent[t] = root;
  uint32_t run = runs[t]; int s = (int)(run & 0xffff), e = (int)(run >> 16);
  int y = r & (HH - 1);
  atomicAdd(&area[root], e - s + 1);
  atomicMax(&clabel[root], y*WW + e + 1);
}

// ---------------- compact roots per image (thread per run slot) -----------
__global__ void k_roots(const int* __restrict__ cnt, const int* __restrict__ parent,
                        const int* __restrict__ area, const int* __restrict__ clabel,
                        int* __restrict__ rootcnt, int* __restrict__ rootA,
                        int* __restrict__ rootL){
  int t = blockIdx.x*blockDim.x + threadIdx.x;
  if (t >= MAXRUNS) return;
  int r = t >> 7, k = t & (RS - 1);
  if (k >= cnt[r]) return;
  if (parent[t] != t) return;                 // roots only
  int a = area[t];
  if (a < 200) return;                        // MIN_AREA
  int b = r >> 9;
  int idx = atomicAdd(&rootcnt[b], 1);
  rootA[b*MAXROOTS + idx] = a;
  rootL[b*MAXROOTS + idx] = clabel[t];
}

// ---------------- top-2 per image (area desc, label asc tie) --------------
__device__ __forceinline__ void ins2(int v, int i, int& v1, int& i1, int& v2, int& i2){
  if (v > v1 || (v == v1 && i < i1)) { v2 = v1; i2 = i1; v1 = v; i1 = i; }
  else if (v > v2 || (v == v2 && i < i2)) { v2 = v; i2 = i; }
}

__global__ void k_top2(const int* __restrict__ rootcnt, const int* __restrict__ rootA,
                       const int* __restrict__ rootL, int* __restrict__ keepL){
  __shared__ int sv1[256], si1[256], sv2[256], si2[256];
  int b = blockIdx.x;
  int n = rootcnt[b];
  int v1 = 0, i1 = INT_MAX, v2 = 0, i2 = INT_MAX;
  for (int k = threadIdx.x; k < n; k += 256)
    ins2(rootA[b*MAXROOTS + k], rootL[b*MAXROOTS + k], v1, i1, v2, i2);
  int t = threadIdx.x;
  sv1[t] = v1; si1[t] = i1; sv2[t] = v2; si2[t] = i2;
  __syncthreads();
  for (int s = 128; s > 0; s >>= 1){
    if (t < s){
      int a1 = sv1[t], b1 = si1[t], a2 = sv2[t], b2 = si2[t];
      ins2(sv1[t+s], si1[t+s], a1, b1, a2, b2);
      ins2(sv2[t+s], si2[t+s], a1, b1, a2, b2);
      sv1[t] = a1; si1[t] = b1; sv2[t] = a2; si2[t] = b2;
    }
    __syncthreads();
  }
  if (t == 0){
    keepL[b*2 + 0] = (sv1[0] > 0) ? si1[0] : 0;   // 0 invalid (labels >= 1)
    keepL[b*2 + 1] = (sv2[0] > 0) ? si2[0] : 0;
  }
}

// ---------------- paint kept runs into bit image (thread per slot) --------
__device__ __forceinline__ u64 rmask(int s, int e){  // bits s..e inclusive
  u64 hi = (e >= 63) ? ~0ULL : ((1ULL << (e + 1)) - 1);
  u64 lo = (1ULL << s) - 1;
  return hi & ~lo;
}

__global__ void k_paint(const uint32_t* __restrict__ runs, const int* __restrict__ cnt,
                        const int* __restrict__ parent, const int* __restrict__ clabel,
                        const int* __restrict__ keepL, u64* __restrict__ keepbits){
  int t = blockIdx.x*blockDim.x + threadIdx.x;
  if (t >= MAXRUNS) return;
  int r = t >> 7, k = t & (RS - 1);
  if (k >= cnt[r]) return;
  int b = r >> 9;
  int L = clabel[parent[t]];                  // parent flattened -> root
  if (L != keepL[b*2] && L != keepL[b*2 + 1]) return;
  uint32_t run = runs[t]; int s = (int)(run & 0xffff), e = (int)(run >> 16);
  int w0 = s >> 6, w1 = e >> 6;
  u64* KB = keepbits + (size_t)r*WPR;
  if (w0 == w1){
    atomicOr(&KB[w0], rmask(s & 63, e & 63));
  } else {
    atomicOr(&KB[w0], rmask(s & 63, 63));
    for (int wi = w0 + 1; wi < w1; ++wi) atomicOr(&KB[wi], ~0ULL);
    atomicOr(&KB[w1], rmask(0, e & 63));
  }
}

// ---------------- expand bits -> f32 (thread per 8 px) ----------------
__global__ void k_expand(const u64* __restrict__ bits, float* __restrict__ out){
  int i = blockIdx.x*blockDim.x + threadIdx.x;
  if (i >= NPIX/8) return;
  u8 by = reinterpret_cast<const u8*>(bits)[i];
  float4 f0, f1;
  f0.x = (float)( by       & 1); f0.y = (float)((by >> 1) & 1);
  f0.z = (float)((by >> 2) & 1); f0.w = (float)((by >> 3) & 1);
  f1.x = (float)((by >> 4) & 1); f1.y = (float)((by >> 5) & 1);
  f1.z = (float)((by >> 6) & 1); f1.w = (float)((by >> 7) & 1);
  float4* O = reinterpret_cast<float4*>(out + (size_t)i*8);
  O[0] = f0; O[1] = f1;
}

// ---------------- launch ----------------
extern "C" void kernel_launch(void* const* d_in, const int* in_sizes, int n_in,
                              void* d_out, int out_size, void* d_ws, size_t ws_size,
                              hipStream_t stream){
  const float* x = (const float*)d_in[0];
  float* out = (float*)d_out;
  char* ws = (char*)d_ws;

  // ws layout (all 256B-aligned)
  const size_t BITS_A_OFF  = 0;                         // 2 MiB
  const size_t BITS_B_OFF  = BITS_A_OFF + 2097152ull;   // 2 MiB
  const size_t KEEP_OFF    = BITS_B_OFF + 2097152ull;   // 2 MiB
  const size_t RUNS_OFF    = KEEP_OFF   + 2097152ull;   // 16 MiB
  const size_t PAR_OFF     = RUNS_OFF   + (size_t)MAXRUNS*4;
  const size_t AREA_OFF    = PAR_OFF    + (size_t)MAXRUNS*4;
  const size_t CLAB_OFF    = AREA_OFF   + (size_t)MAXRUNS*4;
  const size_t CNT_OFF     = CLAB_OFF   + (size_t)MAXRUNS*4;
  const size_t RCNT_OFF    = CNT_OFF    + (size_t)NROWS*4;
  const size_t RA_OFF      = RCNT_OFF   + 1024ull;
  const size_t RL_OFF      = RA_OFF     + (size_t)BB*MAXROOTS*4;
  const size_t KEEPL_OFF   = RL_OFF     + (size_t)BB*MAXROOTS*4;

  u64*      bitsA    = (u64*)(ws + BITS_A_OFF);
  u64*      bitsB    = (u64*)(ws + BITS_B_OFF);
  u64*      keepbits = (u64*)(ws + KEEP_OFF);
  uint32_t* runs     = (uint32_t*)(ws + RUNS_OFF);
  int*      parent   = (int*)(ws + PAR_OFF);
  int*      area     = (int*)(ws + AREA_OFF);
  int*      clabel   = (int*)(ws + CLAB_OFF);
  int*      cnt      = (int*)(ws + CNT_OFF);
  int*      rootcnt  = (int*)(ws + RCNT_OFF);
  int*      rootA    = (int*)(ws + RA_OFF);
  int*      rootL    = (int*)(ws + RL_OFF);
  int*      keepL    = (int*)(ws + KEEPL_OFF);

  const int T = 256;
  dim3 blk(T);

  // init state (every call -> replay-safe)
  k_init<<<dim3(MAXRUNS/T), blk, 0, stream>>>(parent, area, clabel, keepbits, rootcnt);
  // threshold + pack -> bitsA
  k_threshpack<<<dim3(NPIX/T), blk, 0, stream>>>(x, bitsA);
  // open: erode3x3 bitsA->bitsB ; dilate3x3 bitsB->bitsA  (bitsA = opened mask)
  k_bmorph<1, true ><<<dim3(NWORDS/T), blk, 0, stream>>>(bitsA, bitsB);
  k_bmorph<1, false><<<dim3(NWORDS/T), blk, 0, stream>>>(bitsB, bitsA);
  // runs + CCL
  k_runs<<<dim3(NROWS/T), blk, 0, stream>>>(bitsA, runs, cnt);
  k_link<<<dim3(MAXRUNS/T), blk, 0, stream>>>(runs, cnt, parent);
  k_flatten<<<dim3(MAXRUNS/T), blk, 0, stream>>>(runs, cnt, parent, area, clabel);
  k_roots<<<dim3(MAXRUNS/T), blk, 0, stream>>>(cnt, parent, area, clabel, rootcnt, rootA, rootL);
  k_top2<<<dim3(BB), blk, 0, stream>>>(rootcnt, rootA, rootL, keepL);
  k_paint<<<dim3(MAXRUNS/T), blk, 0, stream>>>(runs, cnt, parent, clabel, keepL, keepbits);
  // close: dilate5x5 keepbits->bitsA ; erode5x5 bitsA->bitsB
  k_bmorph<2, false><<<dim3(NWORDS/T), blk, 0, stream>>>(keepbits, bitsA);
  k_bmorph<2, true ><<<dim3(NWORDS/T), blk, 0, stream>>>(bitsA, bitsB);
  // expand -> f32 out
  k_expand<<<dim3(NPIX/8/T), blk, 0, stream>>>(bitsB, out);

  (void)in_sizes; (void)n_in; (void)out_size; (void)ws_size;
}

// Round 6
// 158.456 us; speedup vs baseline: 296.6172x; 1.0610x over previous
//
#include <hip/hip_runtime.h>
#include <stdint.h>
#include <limits.h>

#define BB 64
#define HH 512
#define WW 512
#define WPR 8                  // 64-bit words per row
#define HWP (HH*WW)            // 262144
#define NPIX (BB*HWP)          // 16777216
#define NROWS (BB*HH)          // 32768
#define NWORDS (NROWS*WPR)     // 262144
#define RS 128                 // exact max runs/row in opened mask (len>=3, gap>=1)
#define MAXRUNS (NROWS*RS)     // 4194304
#define MAXROOTS 2048
#define KPR 32                 // link/flatten/roots threads per row (loop if cnt>32)

typedef unsigned char u8;
typedef unsigned long long u64;

// ---------------- threshold + bit-pack, 16 px/thread ----------------
__global__ void k_threshpack(const float* __restrict__ x, u64* __restrict__ bits,
                             int* __restrict__ rootcnt){
  int t = blockIdx.x*blockDim.x + threadIdx.x;      // 0 .. NPIX/16
  if (t < BB) rootcnt[t] = 0;
  const float4* X = reinterpret_cast<const float4*>(x) + (size_t)t*4;
  unsigned m = 0;
  #pragma unroll
  for (int q = 0; q < 4; ++q){
    float4 v = X[q];
    m |= (unsigned)(v.x > -0.5f) << (q*4 + 0);
    m |= (unsigned)(v.y > -0.5f) << (q*4 + 1);
    m |= (unsigned)(v.z > -0.5f) << (q*4 + 2);
    m |= (unsigned)(v.w > -0.5f) << (q*4 + 3);
  }
  int sub = t & 3;
  unsigned p1 = __shfl_xor(m, 1);
  unsigned v32 = (sub & 1) ? (p1 | (m << 16)) : (m | (p1 << 16));
  unsigned p2 = __shfl_xor(v32, 2);
  if ((sub & 3) == 0){
    u64 w = (u64)v32 | ((u64)p2 << 32);
    bits[t >> 2] = w;
  }
}

// ---------------- helpers for bit morphology ----------------
__device__ __forceinline__ u64 hshift3_and(u64 c, u64 l, u64 r){
  return c & ((c << 1) | (l >> 63)) & ((c >> 1) | (r << 63));
}
__device__ __forceinline__ u64 hshift3_or(u64 c, u64 l, u64 r){
  return c | (c << 1) | (l >> 63) | (c >> 1) | (r << 63);
}
__device__ __forceinline__ u64 hshift5_and(u64 c, u64 l, u64 r){
  return hshift3_and(c, l, r) & ((c << 2) | (l >> 62)) & ((c >> 2) | (r << 62));
}
__device__ __forceinline__ u64 hshift5_or(u64 c, u64 l, u64 r){
  return hshift3_or(c, l, r) | (c << 2) | (l >> 62) | (c >> 2) | (r << 62);
}

// load word (row, wi) with image-vertical zero pad
__device__ __forceinline__ u64 ldw(const u64* __restrict__ in, int img, int rowInImg, int wi){
  if ((unsigned)rowInImg >= (unsigned)HH) return 0ULL;
  if ((unsigned)wi >= (unsigned)WPR) return 0ULL;
  return in[((size_t)img*HH + rowInImg)*WPR + wi];
}

// ---------------- fused open: erode3x3 then dilate3x3 ----------------
#define ORPB 64
__global__ __launch_bounds__(256)
void k_open(const u64* __restrict__ in, u64* __restrict__ out){
  __shared__ u64 er[ORPB + 2][WPR];
  int R0 = blockIdx.x * ORPB;                 // first center row (global)
  int img = R0 >> 9;
  int y0 = R0 & (HH - 1);
  // phase A: erode rows y0-1 .. y0+ORPB into LDS
  for (int s = threadIdx.x; s < (ORPB + 2)*WPR; s += 256){
    int rr = (s >> 3) - 1 + y0;               // row in image
    int wi = s & 7;
    u64 acc = ~0ULL;
    #pragma unroll
    for (int dy = -1; dy <= 1; ++dy){
      int yy = rr + dy;
      u64 c = ldw(in, img, yy, wi);
      u64 l = ldw(in, img, yy, wi - 1);
      u64 r = ldw(in, img, yy, wi + 1);
      u64 h = ((unsigned)yy < (unsigned)HH) ? hshift3_and(c, l, r) : 0ULL;
      acc &= h;
    }
    if ((unsigned)rr >= (unsigned)HH) acc = 0ULL;
    er[s >> 3][wi] = acc;
  }
  __syncthreads();
  // phase B: dilate3x3 of eroded, center rows
  for (int s = threadIdx.x; s < ORPB*WPR; s += 256){
    int ri = s >> 3;                          // 0..ORPB-1
    int wi = s & 7;
    u64 acc = 0ULL;
    #pragma unroll
    for (int dy = -1; dy <= 1; ++dy){
      int li = ri + 1 + dy;                   // LDS row index
      u64 c = er[li][wi];
      u64 l = (wi > 0) ? er[li][wi-1] : 0ULL;
      u64 r = (wi < 7) ? er[li][wi+1] : 0ULL;
      acc |= hshift3_or(c, l, r);
    }
    out[(size_t)(R0 + ri)*WPR + wi] = acc;
  }
}

// ---------------- run extraction + per-slot init (thread per row) ---------
__global__ void k_runs(const u64* __restrict__ bitrow, uint32_t* __restrict__ runs,
                       int* __restrict__ cnt, int* __restrict__ parent,
                       int* __restrict__ area, int* __restrict__ clabel){
  int r = blockIdx.x*blockDim.x + threadIdx.x;
  if (r >= NROWS) return;
  const u64* W = bitrow + (size_t)r*WPR;
  u64 w[8];
  #pragma unroll
  for (int i = 0; i < 8; ++i) w[i] = W[i];
  int base = r*RS;
  int k = 0;
  int pending = -1;
  u64 carry = 0;
  #pragma unroll
  for (int wi = 0; wi < 8; ++wi){
    u64 b = w[wi];
    u64 nb0 = (wi < 7) ? (w[wi+1] & 1ULL) : 0ULL;
    u64 starts = b & ~((b << 1) | carry);
    u64 ends   = b & ~(b >> 1);
    if (nb0) ends &= ~(1ULL << 63);
    carry = b >> 63;
    while (ends){
      int e = __ffsll((long long)ends) - 1; ends &= ends - 1;
      int s;
      if (pending >= 0){ s = pending; pending = -1; }
      else { s = wi*64 + (__ffsll((long long)starts) - 1); starts &= starts - 1; }
      int id = base + k;
      runs[id] = (uint32_t)s | ((uint32_t)(wi*64 + e) << 16);
      parent[id] = id; area[id] = 0; clabel[id] = 0;
      k++;
    }
    if (starts) pending = wi*64 + (__ffsll((long long)starts) - 1);
  }
  cnt[r] = k;
}

// ---------------- union-find: path-HALVING find (provably terminating) ----
// Invariant: parent[x] <= x under all writes (init, union-min, halving-min).
// Each non-returning iteration strictly decreases p -> no livelock even with
// concurrent unions (round-4's full compression loop could livelock when a
// found root got merged under a smaller root mid-compression).
__device__ __forceinline__ int uf_find(int* parent, int p){
  while (true){
    int q = parent[p];
    int g = parent[q];
    if (q == g) return q;
    atomicMin(&parent[p], g);     // monotone halving write: race-safe
    p = g;
  }
}
__device__ __forceinline__ void uf_union(int* parent, int a, int b){
  while (true){
    a = uf_find(parent, a);
    b = uf_find(parent, b);
    if (a == b) return;
    if (a < b){ int t = a; a = b; b = t; }     // a = hi, b = lo
    int old = atomicMin(&parent[a], b);
    if (old == a) return;
    a = old;                                    // a strictly decreases -> terminates
  }
}

// ---------------- link runs to previous row (KPR threads per row) ---------
__global__ void k_link(const uint32_t* __restrict__ runs, const int* __restrict__ cnt,
                       int* __restrict__ parent){
  int t = blockIdx.x*blockDim.x + threadIdx.x;
  if (t >= NROWS*KPR) return;
  int r = t / KPR, k0 = t % KPR;
  int y = r & (HH - 1);
  if (y == 0) return;
  int ca = cnt[r];
  int cb = cnt[r-1];
  if (cb == 0) return;
  const uint32_t* RB = runs + (size_t)(r-1)*RS;
  for (int k = k0; k < ca; k += KPR){
    int id = r*RS + k;
    uint32_t ra = runs[id]; int sA = (int)(ra & 0xffff), eA = (int)(ra >> 16);
    // first j with endB_j >= sA-1 (ends strictly increasing)
    int lo = 0, hi = cb, target = sA - 1;
    while (lo < hi){
      int mid = (lo + hi) >> 1;
      if ((int)(RB[mid] >> 16) < target) lo = mid + 1; else hi = mid;
    }
    for (int j = lo; j < cb; ++j){
      uint32_t rb = RB[j];
      if ((int)(rb & 0xffff) > eA + 1) break;
      uf_union(parent, id, (r-1)*RS + j);
    }
  }
}

// ---------------- flatten + accumulate ----------------
__global__ void k_flatten(const uint32_t* __restrict__ runs, const int* __restrict__ cnt,
                          int* __restrict__ parent, int* __restrict__ area,
                          int* __restrict__ clabel){
  int t = blockIdx.x*blockDim.x + threadIdx.x;
  if (t >= NROWS*KPR) return;
  int r = t / KPR, k0 = t % KPR;
  int n = cnt[r];
  int y = r & (HH - 1);
  for (int k = k0; k < n; k += KPR){
    int id = r*RS + k;
    int root = uf_find(parent, id);
    parent[id] = root;    // forest static here: all writers store the same root
    uint32_t run = runs[id]; int s = (int)(run & 0xffff), e = (int)(run >> 16);
    atomicAdd(&area[root], e - s + 1);
    atomicMax(&clabel[root], y*WW + e + 1);
  }
}

// ---------------- compact roots per image ----------------
__global__ void k_roots(const int* __restrict__ cnt, const int* __restrict__ parent,
                        const int* __restrict__ area, const int* __restrict__ clabel,
                        int* __restrict__ rootcnt, int* __restrict__ rootA,
                        int* __restrict__ rootL){
  int t = blockIdx.x*blockDim.x + threadIdx.x;
  if (t >= NROWS*KPR) return;
  int r = t / KPR, k0 = t % KPR;
  int n = cnt[r];
  int b = r >> 9;
  for (int k = k0; k < n; k += KPR){
    int id = r*RS + k;
    if (parent[id] != id) continue;
    int a = area[id];
    if (a < 200) continue;                   // MIN_AREA
    int idx = atomicAdd(&rootcnt[b], 1);
    rootA[b*MAXROOTS + idx] = a;
    rootL[b*MAXROOTS + idx] = clabel[id];
  }
}

// ---------------- top-2 per image (area desc, label asc tie) --------------
__device__ __forceinline__ void ins2(int v, int i, int& v1, int& i1, int& v2, int& i2){
  if (v > v1 || (v == v1 && i < i1)) { v2 = v1; i2 = i1; v1 = v; i1 = i; }
  else if (v > v2 || (v == v2 && i < i2)) { v2 = v; i2 = i; }
}

__global__ void k_top2(const int* __restrict__ rootcnt, const int* __restrict__ rootA,
                       const int* __restrict__ rootL, int* __restrict__ keepL){
  __shared__ int sv1[64], si1[64], sv2[64], si2[64];
  int b = blockIdx.x;
  int n = rootcnt[b];
  int v1 = 0, i1 = INT_MAX, v2 = 0, i2 = INT_MAX;
  for (int k = threadIdx.x; k < n; k += 64)
    ins2(rootA[b*MAXROOTS + k], rootL[b*MAXROOTS + k], v1, i1, v2, i2);
  int t = threadIdx.x;
  sv1[t] = v1; si1[t] = i1; sv2[t] = v2; si2[t] = i2;
  __syncthreads();
  for (int s = 32; s > 0; s >>= 1){
    if (t < s){
      int a1 = sv1[t], b1 = si1[t], a2 = sv2[t], b2 = si2[t];
      ins2(sv1[t+s], si1[t+s], a1, b1, a2, b2);
      ins2(sv2[t+s], si2[t+s], a1, b1, a2, b2);
      sv1[t] = a1; si1[t] = b1; sv2[t] = a2; si2[t] = b2;
    }
    __syncthreads();
  }
  if (t == 0){
    keepL[b*2 + 0] = (sv1[0] > 0) ? si1[0] : 0;   // 0 invalid (labels >= 1)
    keepL[b*2 + 1] = (sv2[0] > 0) ? si2[0] : 0;
  }
}

// ---------------- build keep bit image directly (thread per row) ----------
__device__ __forceinline__ u64 rmask(int s, int e){  // bits s..e inclusive
  u64 hi = (e >= 63) ? ~0ULL : ((1ULL << (e + 1)) - 1);
  u64 lo = (1ULL << s) - 1;
  return hi & ~lo;
}

__global__ void k_keepw(const uint32_t* __restrict__ runs, const int* __restrict__ cnt,
                        const int* __restrict__ parent, const int* __restrict__ clabel,
                        const int* __restrict__ keepL, u64* __restrict__ keepbits){
  int r = blockIdx.x*blockDim.x + threadIdx.x;
  if (r >= NROWS) return;
  int b = r >> 9;
  int L1 = keepL[b*2], L2 = keepL[b*2 + 1];
  u64 wbits[8] = {0,0,0,0,0,0,0,0};
  int n = cnt[r];
  for (int k = 0; k < n; ++k){
    int id = r*RS + k;
    int L = clabel[parent[id]];
    if (L != L1 && L != L2) continue;
    uint32_t run = runs[id]; int s = (int)(run & 0xffff), e = (int)(run >> 16);
    int w0 = s >> 6, w1 = e >> 6;
    if (w0 == w1) wbits[w0] |= rmask(s & 63, e & 63);
    else {
      wbits[w0] |= rmask(s & 63, 63);
      for (int wi = w0 + 1; wi < w1; ++wi) wbits[wi] = ~0ULL;
      wbits[w1] |= rmask(0, e & 63);
    }
  }
  u64* O = keepbits + (size_t)r*WPR;
  #pragma unroll
  for (int wi = 0; wi < 8; ++wi) O[wi] = wbits[wi];
}

// ---------------- fused close (dilate5+erode5) + expand to f32 ------------
#define CRPB 32
__global__ __launch_bounds__(256)
void k_closeexpand(const u64* __restrict__ in, float* __restrict__ out){
  __shared__ u64 dil[CRPB + 4][WPR];
  __shared__ u64 ero[CRPB][WPR];
  int R0 = blockIdx.x * CRPB;                 // first center row (global)
  int img = R0 >> 9;
  int y0 = R0 & (HH - 1);
  // phase A: dilate5 rows y0-2 .. y0+CRPB+1
  for (int s = threadIdx.x; s < (CRPB + 4)*WPR; s += 256){
    int rr = (s >> 3) - 2 + y0;
    int wi = s & 7;
    u64 acc = 0ULL;
    #pragma unroll
    for (int dy = -2; dy <= 2; ++dy){
      int yy = rr + dy;
      u64 c = ldw(in, img, yy, wi);
      u64 l = ldw(in, img, yy, wi - 1);
      u64 r = ldw(in, img, yy, wi + 1);
      acc |= hshift5_or(c, l, r);
    }
    dil[s >> 3][wi] = acc;                     // rows outside image: inputs all 0 -> 0
  }
  __syncthreads();
  // phase B: erode5 center rows (zero pad outside image via y-check)
  for (int s = threadIdx.x; s < CRPB*WPR; s += 256){
    int ri = s >> 3;
    int wi = s & 7;
    int y = y0 + ri;
    u64 acc = ~0ULL;
    #pragma unroll
    for (int dy = -2; dy <= 2; ++dy){
      int yy = y + dy;
      u64 h;
      if ((unsigned)yy >= (unsigned)HH) h = 0ULL;
      else {
        int li = ri + 2 + dy;
        u64 c = dil[li][wi];
        u64 l = (wi > 0) ? dil[li][wi-1] : 0ULL;
        u64 r = (wi < 7) ? dil[li][wi+1] : 0ULL;
        h = hshift5_and(c, l, r);
      }
      acc &= h;
    }
    ero[ri][wi] = acc;
  }
  __syncthreads();
  // phase C: expand to f32, coalesced float4 stores
  float4* O = reinterpret_cast<float4*>(out + (size_t)R0*WW);
  for (int i = threadIdx.x; i < CRPB*WW/4; i += 256){
    int px = i * 4;
    int row = px >> 9;
    int x = px & (WW - 1);
    u64 word = ero[row][x >> 6];
    unsigned nib = (unsigned)((word >> (x & 63)) & 0xFULL);
    float4 f;
    f.x = (float)( nib       & 1);
    f.y = (float)((nib >> 1) & 1);
    f.z = (float)((nib >> 2) & 1);
    f.w = (float)((nib >> 3) & 1);
    O[i] = f;
  }
}

// ---------------- launch ----------------
extern "C" void kernel_launch(void* const* d_in, const int* in_sizes, int n_in,
                              void* d_out, int out_size, void* d_ws, size_t ws_size,
                              hipStream_t stream){
  const float* x = (const float*)d_in[0];
  float* out = (float*)d_out;
  char* ws = (char*)d_ws;

  const size_t BITS_A_OFF  = 0;                         // 2 MiB (thresh / keep)
  const size_t BITS_B_OFF  = BITS_A_OFF + 2097152ull;   // 2 MiB (opened mask)
  const size_t RUNS_OFF    = BITS_B_OFF + 2097152ull;   // 16 MiB
  const size_t PAR_OFF     = RUNS_OFF   + (size_t)MAXRUNS*4;
  const size_t AREA_OFF    = PAR_OFF    + (size_t)MAXRUNS*4;
  const size_t CLAB_OFF    = AREA_OFF   + (size_t)MAXRUNS*4;
  const size_t CNT_OFF     = CLAB_OFF   + (size_t)MAXRUNS*4;
  const size_t RCNT_OFF    = CNT_OFF    + (size_t)NROWS*4;
  const size_t RA_OFF      = RCNT_OFF   + 1024ull;
  const size_t RL_OFF      = RA_OFF     + (size_t)BB*MAXROOTS*4;
  const size_t KEEPL_OFF   = RL_OFF     + (size_t)BB*MAXROOTS*4;

  u64*      bitsA    = (u64*)(ws + BITS_A_OFF);
  u64*      bitsB    = (u64*)(ws + BITS_B_OFF);
  uint32_t* runs     = (uint32_t*)(ws + RUNS_OFF);
  int*      parent   = (int*)(ws + PAR_OFF);
  int*      area     = (int*)(ws + AREA_OFF);
  int*      clabel   = (int*)(ws + CLAB_OFF);
  int*      cnt      = (int*)(ws + CNT_OFF);
  int*      rootcnt  = (int*)(ws + RCNT_OFF);
  int*      rootA    = (int*)(ws + RA_OFF);
  int*      rootL    = (int*)(ws + RL_OFF);
  int*      keepL    = (int*)(ws + KEEPL_OFF);

  const int T = 256;
  dim3 blk(T);

  // 1) threshold+pack -> bitsA (also zeroes rootcnt)
  k_threshpack<<<dim3(NPIX/16/T), blk, 0, stream>>>(x, bitsA, rootcnt);
  // 2) fused open: erode3+dilate3 bitsA -> bitsB
  k_open<<<dim3(NROWS/ORPB), blk, 0, stream>>>(bitsA, bitsB);
  // 3) runs + per-slot init
  k_runs<<<dim3(NROWS/T), blk, 0, stream>>>(bitsB, runs, cnt, parent, area, clabel);
  // 4) CCL
  k_link   <<<dim3(NROWS*KPR/T), blk, 0, stream>>>(runs, cnt, parent);
  k_flatten<<<dim3(NROWS*KPR/T), blk, 0, stream>>>(runs, cnt, parent, area, clabel);
  k_roots  <<<dim3(NROWS*KPR/T), blk, 0, stream>>>(cnt, parent, area, clabel,
                                                   rootcnt, rootA, rootL);
  k_top2<<<dim3(BB), dim3(64), 0, stream>>>(rootcnt, rootA, rootL, keepL);
  // 5) keep-bit image -> bitsA
  k_keepw<<<dim3(NROWS/T), blk, 0, stream>>>(runs, cnt, parent, clabel, keepL, bitsA);
  // 6) fused close + expand -> f32 out
  k_closeexpand<<<dim3(NROWS/CRPB), blk, 0, stream>>>(bitsA, out);

  (void)in_sizes; (void)n_in; (void)out_size; (void)ws_size;
}